// Round 5
// baseline (128.178 us; speedup 1.0000x reference)
//
#include <hip/hip_runtime.h>
#include <stdint.h>

// Problem constants (B=1, L=256, C=128, N=4, TN=4)
#define LLTOT 65536
#define CDIM  128
#define TPIX  32
#define TILES 4
#define NBLK  (LLTOT / (TPIX * TILES))   // 512 blocks

typedef float f32x4 __attribute__((ext_vector_type(4)));
typedef short s16x8 __attribute__((ext_vector_type(8)));

#define MFMA16(a, b, c) __builtin_amdgcn_mfma_f32_16x16x32_bf16((a), (b), (c), 0, 0, 0)

// raw barrier: drain LDS only (stores keep streaming across barriers)
#define SYNCB() do {                                        \
    __builtin_amdgcn_sched_barrier(0);                      \
    asm volatile("s_waitcnt lgkmcnt(0)" ::: "memory");      \
    __builtin_amdgcn_s_barrier();                           \
    __builtin_amdgcn_sched_barrier(0);                      \
} while (0)

// ---- persistent device scratch (weights only) ----
__device__ __align__(16) unsigned short g_weff[32 * 128];   // folded routing weights, bf16
__device__ __align__(16) unsigned short g_w1g[512 * 128];   // W1 * ln_g, bf16
__device__ __align__(16) unsigned short g_w2[128 * 512];    // W2, bf16
__device__ __align__(16) float g_hA[512];                   // b1 + W1 @ ln_b
__device__ __align__(16) float g_w1gs[512];                 // row sums of W1*ln_g

__device__ __forceinline__ unsigned short f2bf(float f) {
    union { float f; uint32_t u; } v; v.f = f;
    uint32_t u = v.u;
    return (unsigned short)((u + 0x7FFFu + ((u >> 16) & 1u)) >> 16);
}
__device__ __forceinline__ float bf2f(uint32_t lo16) { return __uint_as_float(lo16 << 16); }

__device__ __forceinline__ float fast_tanh(float x) {
    float cx = fminf(fmaxf(x, -10.f), 10.f);
    float e = __expf(2.f * cx);
    return (e - 1.f) * __builtin_amdgcn_rcpf(e + 1.f);
}
__device__ __forceinline__ float fast_sig(float z) {
    return __builtin_amdgcn_rcpf(1.f + __expf(-z));
}

// ---- prep: fold weights, convert to bf16 ----
__global__ void prep_kernel(const float* __restrict__ Wpre, const float* __restrict__ Wpost,
                            const float* __restrict__ Wres, const float* __restrict__ W1,
                            const float* __restrict__ W2, const float* __restrict__ ln_g,
                            const float* __restrict__ ln_b, const float* __restrict__ b1) {
    int b = blockIdx.x, t = threadIdx.x;
    if (b == 264) {
        int j = t;   // 512 threads
        float sg = 0.f, sb = 0.f;
        const float* row = W1 + j * 128;
        #pragma unroll 4
        for (int c = 0; c < 128; c += 4) {
            float4 wv = *(const float4*)(row + c);
            float4 gv = *(const float4*)(ln_g + c);
            float4 bv = *(const float4*)(ln_b + c);
            sg += wv.x*gv.x + wv.y*gv.y + wv.z*gv.z + wv.w*gv.w;
            sb += wv.x*bv.x + wv.y*bv.y + wv.z*bv.z + wv.w*bv.w;
        }
        g_hA[j]   = b1[j] + sb;
        g_w1gs[j] = sg;
        return;
    }
    int idx = b * 512 + t;
    if (idx < 4096) {
        int o = idx >> 7, c = idx & 127;
        float v = 0.f;
        if (o < 4)        v = Wpre[o*512+c] + Wpre[o*512+128+c] + Wpre[o*512+256+c] + Wpre[o*512+384+c];
        else if (o < 8)   { int j = o - 4;  v = Wpost[j*512+c] + Wpost[j*512+128+c] + Wpost[j*512+256+c] + Wpost[j*512+384+c]; }
        else if (o < 24)  { int j = o - 8;  v = Wres[j*512+c] + Wres[j*512+128+c] + Wres[j*512+256+c] + Wres[j*512+384+c]; }
        g_weff[idx] = f2bf(v);
    } else if (idx < 69632) {
        int r = idx - 4096; int c = r & 127;
        g_w1g[r] = f2bf(W1[r] * ln_g[c]);
    } else if (idx < 135168) {
        g_w2[idx - 69632] = f2bf(W2[idx - 69632]);
    }
}

// ---- fused pipelined kernel: 4 tiles/block, 2 barriers/tile ----
__global__ void __launch_bounds__(512, 2) fused_kernel(
    const float* __restrict__ p, const float* __restrict__ p_mask,
    const float* __restrict__ b_pre, const float* __restrict__ b_post, const float* __restrict__ b_res,
    const float* __restrict__ a_pre, const float* __restrict__ a_post, const float* __restrict__ a_res,
    const float* __restrict__ b2g, float* __restrict__ out)
{
    __shared__ __align__(16) unsigned short h_s[TPIX * 512];       // 32 KB bf16 relu(h), swizzle <<5
    __shared__ __align__(16) unsigned short p_s[3][TPIX * CDIM];   // 24 KB bf16 p, swizzle <<4
    __shared__ __align__(16) float y_s[TPIX * 32];                 // 4 KB routing logits
    __shared__ __align__(16) float hA_s[512], W1gs_s[512];         // 4 KB
    __shared__ __align__(16) float Asc_s[2][TPIX * 4], Bsc_s[2][TPIX * 4];
    __shared__ __align__(16) float rms_s[2][TPIX], mv_s[2][2][TPIX];
    __shared__ __align__(16) float si_s[TPIX], mi_s[TPIX];
    __shared__ float cpar_s[32];   // [0:4) b_pre, [4:8) b_post, [8:24) b_res, 24..26 alphas

    const int t0 = threadIdx.x;
    const int w  = t0 >> 6, l = t0 & 63, lr = l & 15, lk = l >> 4;
    const size_t blk0 = (size_t)blockIdx.x * (TILES * TPIX);   // first pixel of block

    // per-lane constants
    const int c0 = w * 16 + lk * 4;                 // GEMM2 output channel base
    float4 b2v = ((const float4*)b2g)[w * 4 + lk];

    // stats + bf16 p staging: pixel = w*4 + (l>>4), 8 floats per lane
    auto do_stats = [&](int tt, float4 va, float4 vb) {
        int pix = w * 4 + (l >> 4), ci = l & 15;
        float s  = va.x + va.y + va.z + va.w + vb.x + vb.y + vb.z + vb.w;
        float ss = va.x*va.x + va.y*va.y + va.z*va.z + va.w*va.w
                 + vb.x*vb.x + vb.y*vb.y + vb.z*vb.z + vb.w*vb.w;
        s += __shfl_xor(s, 1); ss += __shfl_xor(ss, 1);
        s += __shfl_xor(s, 2); ss += __shfl_xor(ss, 2);
        s += __shfl_xor(s, 4); ss += __shfl_xor(ss, 4);
        s += __shfl_xor(s, 8); ss += __shfl_xor(ss, 8);
        if (ci == 0) {
            float mu = s * (1.f / 128.f), mq = ss * (1.f / 128.f);
            rms_s[tt & 1][pix]   = rsqrtf(mq + 1.1920929e-07f);
            mv_s[tt & 1][0][pix] = mu;
            mv_s[tt & 1][1][pix] = mq - mu * mu;
        }
        uint4 u;
        u.x = f2bf(va.x) | ((uint32_t)f2bf(va.y) << 16);
        u.y = f2bf(va.z) | ((uint32_t)f2bf(va.w) << 16);
        u.z = f2bf(vb.x) | ((uint32_t)f2bf(vb.y) << 16);
        u.w = f2bf(vb.z) | ((uint32_t)f2bf(vb.w) << 16);
        uint32_t off = (uint32_t)(pix * 256 + ci * 16) ^ ((pix & 7) << 4);
        *(uint4*)((char*)p_s[tt % 3] + off) = u;
    };

    // ---- prologue: params + tile 0 ----
    {
        if (t0 < 128)       ((float4*)hA_s)[t0]         = ((const float4*)g_hA)[t0];
        else if (t0 < 256)  ((float4*)W1gs_s)[t0 - 128] = ((const float4*)g_w1gs)[t0 - 128];
        else if (t0 < 260)  cpar_s[t0 - 256]      = b_pre[t0 - 256];
        else if (t0 < 264)  cpar_s[4 + t0 - 260]  = b_post[t0 - 260];
        else if (t0 < 280)  cpar_s[8 + t0 - 264]  = b_res[t0 - 264];
        else if (t0 == 280) cpar_s[24] = a_pre[0];
        else if (t0 == 281) cpar_s[25] = a_post[0];
        else if (t0 == 282) cpar_s[26] = a_res[0];
        int pix = w * 4 + (l >> 4), ci = l & 15;
        const float* src = p + (blk0 + pix) * 128 + ci * 8;
        float4 va = *(const float4*)src;
        float4 vb = *(const float4*)(src + 4);
        do_stats(0, va, vb);
    }
    SYNCB();

    // ---- main loop: t = tile being GEMM1'd; t-1 = tile being GEMM2'd/stored ----
    for (int t = 0; t <= TILES; ++t) {
        f32x4 acc1[4][2] = {};

        // -- phase A --
        if (t < TILES) {
            // GEMM1(t): h_pre[j, i] partials, j = w*64 + jt*16 + lr
            const char* wbase = (const char*)g_w1g + (w * 64 + lr) * 256 + lk * 16;
            const char* pb = (const char*)p_s[t % 3];
            #pragma unroll
            for (int kk = 0; kk < 4; ++kk) {
                s16x8 b0, b1;
                {
                    uint32_t off = (uint32_t)(lr * 256 + kk * 64 + lk * 16) ^ ((lr & 7) << 4);
                    b0 = *(const s16x8*)(pb + off);
                }
                {
                    int row = 16 + lr;
                    uint32_t off = (uint32_t)(row * 256 + kk * 64 + lk * 16) ^ ((row & 7) << 4);
                    b1 = *(const s16x8*)(pb + off);
                }
                #pragma unroll
                for (int jt = 0; jt < 4; ++jt) {
                    s16x8 a = *(const s16x8*)(wbase + jt * 4096 + kk * 64);
                    acc1[jt][0] = MFMA16(a, b0, acc1[jt][0]);
                    acc1[jt][1] = MFMA16(a, b1, acc1[jt][1]);
                }
            }
        }

        // routing + Sinkhorn for tile t on waves 0-1 (16 pixels each)
        if (t < TILES && w < 2) {
            const char* pb = (const char*)p_s[t % 3];
            f32x4 racc[2] = {};
            #pragma unroll
            for (int kk = 0; kk < 4; ++kk) {
                int row = w * 16 + lr;
                uint32_t off = (uint32_t)(row * 256 + kk * 64 + lk * 16) ^ ((row & 7) << 4);
                s16x8 bfr = *(const s16x8*)(pb + off);
                #pragma unroll
                for (int jt = 0; jt < 2; ++jt) {
                    s16x8 a = *(const s16x8*)((const char*)g_weff + (jt * 16 + lr) * 256 + kk * 64 + lk * 16);
                    racc[jt] = MFMA16(a, bfr, racc[jt]);
                }
            }
            #pragma unroll
            for (int jt = 0; jt < 2; ++jt)
                *(f32x4*)(y_s + (w * 16 + (l & 15)) * 32 + jt * 16 + lk * 4) = racc[jt];

            // activations + Sinkhorn: pix = w*16 + (l>>2), m = l&3
            int pix = w * 16 + (l >> 2), m = l & 3;
            float apre = cpar_s[24], apost = cpar_s[25], ares = cpar_s[26];
            float rv   = rms_s[t & 1][pix];
            float mean = mv_s[t & 1][0][pix];
            float var  = mv_s[t & 1][1][pix];
            float msk  = p_mask[blk0 + (size_t)t * 32 + pix];
            const float* yp = y_s + pix * 32;
            float hpre = fast_sig(apre * fast_tanh(rv * yp[m]) + cpar_s[m]);
            float sp = hpre;
            sp += __shfl_xor(sp, 1); sp += __shfl_xor(sp, 2);
            float hp = 2.f * fast_sig(apost * fast_tanh(rv * yp[4 + m]) + cpar_s[4 + m]);
            float M0 = __expf(ares * fast_tanh(rv * yp[8 + m*4 + 0]) + cpar_s[8 + m*4 + 0]);
            float M1 = __expf(ares * fast_tanh(rv * yp[8 + m*4 + 1]) + cpar_s[8 + m*4 + 1]);
            float M2 = __expf(ares * fast_tanh(rv * yp[8 + m*4 + 2]) + cpar_s[8 + m*4 + 2]);
            float M3 = __expf(ares * fast_tanh(rv * yp[8 + m*4 + 3]) + cpar_s[8 + m*4 + 3]);
            #pragma unroll 1
            for (int it2 = 0; it2 < 20; ++it2) {
                float ri = __builtin_amdgcn_rcpf(M0 + M1 + M2 + M3);
                M0 *= ri; M1 *= ri; M2 *= ri; M3 *= ri;
                float cc0 = M0, cc1 = M1, cc2 = M2, cc3 = M3;
                cc0 += __shfl_xor(cc0, 1); cc1 += __shfl_xor(cc1, 1); cc2 += __shfl_xor(cc2, 1); cc3 += __shfl_xor(cc3, 1);
                cc0 += __shfl_xor(cc0, 2); cc1 += __shfl_xor(cc1, 2); cc2 += __shfl_xor(cc2, 2); cc3 += __shfl_xor(cc3, 2);
                M0 *= __builtin_amdgcn_rcpf(cc0); M1 *= __builtin_amdgcn_rcpf(cc1);
                M2 *= __builtin_amdgcn_rcpf(cc2); M3 *= __builtin_amdgcn_rcpf(cc3);
            }
            float r = M0 + M1 + M2 + M3;
            Asc_s[t & 1][pix * 4 + m] = r + hp * sp;
            Bsc_s[t & 1][pix * 4 + m] = hp * msk;
            if (m == 0) {
                float istd = rsqrtf(sp * sp * var + 1e-5f);
                si_s[pix] = sp * istd;
                mi_s[pix] = sp * mean * istd;
            }
        }

        // GEMM2(t-1) + epilogue(t-1), D kept in registers
        if (t >= 1) {
            int u = t - 1;
            const char* w2base = (const char*)g_w2 + (w * 16 + lr) * 1024 + lk * 16;
            f32x4 acc2[2] = {};
            #pragma unroll 4
            for (int kk = 0; kk < 16; ++kk) {
                s16x8 a = *(const s16x8*)(w2base + kk * 64);
                s16x8 b0, b1;
                {
                    uint32_t off = (uint32_t)(lr * 1024 + kk * 64 + lk * 16) ^ ((lr & 7) << 5);
                    b0 = *(const s16x8*)((const char*)h_s + off);
                }
                {
                    int i = 16 + lr;
                    uint32_t off = (uint32_t)(i * 1024 + kk * 64 + lk * 16) ^ ((i & 7) << 5);
                    b1 = *(const s16x8*)((const char*)h_s + off);
                }
                acc2[0] = MFMA16(a, b0, acc2[0]);
                acc2[1] = MFMA16(a, b1, acc2[1]);
            }
            const char* pbu = (const char*)p_s[u % 3];
            float* og = out + (blk0 + (size_t)u * 32) * 512;
            #pragma unroll
            for (int it = 0; it < 2; ++it) {
                int i = it * 16 + lr;
                uint32_t poff = (uint32_t)(i * 256 + c0 * 2) ^ ((i & 7) << 4);
                uint2 pb2 = *(const uint2*)(pbu + poff);
                float p0 = bf2f(pb2.x & 0xffffu), p1 = __uint_as_float(pb2.x & 0xffff0000u);
                float p2 = bf2f(pb2.y & 0xffffu), p3 = __uint_as_float(pb2.y & 0xffff0000u);
                float4 Av4 = *(const float4*)(&Asc_s[u & 1][i * 4]);
                float4 Bv4 = *(const float4*)(&Bsc_s[u & 1][i * 4]);
                float d0 = acc2[it][0] + b2v.x, d1 = acc2[it][1] + b2v.y;
                float d2 = acc2[it][2] + b2v.z, d3 = acc2[it][3] + b2v.w;
                #pragma unroll
                for (int m = 0; m < 4; ++m) {
                    float Av = (&Av4.x)[m], Bv = (&Bv4.x)[m];
                    f32x4 o;
                    o[0] = Av * p0 + Bv * d0;
                    o[1] = Av * p1 + Bv * d1;
                    o[2] = Av * p2 + Bv * d2;
                    o[3] = Av * p3 + Bv * d3;
                    __builtin_nontemporal_store(o, (f32x4*)(og + (size_t)i * 512 + m * 128 + c0));
                }
            }
        }

        // prefetch p(t+1) into registers (consumed after the barrier)
        float4 pva, pvb;
        if (t + 1 < TILES) {
            int pix = w * 4 + (l >> 4), ci = l & 15;
            const float* src = p + (blk0 + (size_t)(t + 1) * 32 + pix) * 128 + ci * 8;
            pva = *(const float4*)src;
            pvb = *(const float4*)(src + 4);
        }

        SYNCB();

        // -- phase B --
        if (t < TILES) {
            // fold LN scalars + bias + relu -> bf16 h_s
            #pragma unroll
            for (int jt = 0; jt < 4; ++jt) {
                int j0 = w * 64 + jt * 16 + lk * 4;
                float4 wg = *(const float4*)(W1gs_s + j0);
                float4 ha = *(const float4*)(hA_s + j0);
                #pragma unroll
                for (int it = 0; it < 2; ++it) {
                    int i = it * 16 + lr;
                    float si = si_s[i], mi = mi_s[i];
                    f32x4 v = acc1[jt][it];
                    float h0 = fmaxf(fmaf(si, v[0], fmaf(-mi, wg.x, ha.x)), 0.f);
                    float h1 = fmaxf(fmaf(si, v[1], fmaf(-mi, wg.y, ha.y)), 0.f);
                    float h2 = fmaxf(fmaf(si, v[2], fmaf(-mi, wg.z, ha.z)), 0.f);
                    float h3 = fmaxf(fmaf(si, v[3], fmaf(-mi, wg.w, ha.w)), 0.f);
                    uint2 uu;
                    uu.x = f2bf(h0) | ((uint32_t)f2bf(h1) << 16);
                    uu.y = f2bf(h2) | ((uint32_t)f2bf(h3) << 16);
                    uint32_t off = (uint32_t)(i * 1024 + j0 * 2) ^ ((i & 7) << 5);
                    *(uint2*)((char*)h_s + off) = uu;
                }
            }
        }
        if (t + 1 < TILES) {
            do_stats(t + 1, pva, pvb);
        }

        SYNCB();
    }
}

extern "C" void kernel_launch(void* const* d_in, const int* in_sizes, int n_in,
                              void* d_out, int out_size, void* d_ws, size_t ws_size,
                              hipStream_t stream) {
    const float* p      = (const float*)d_in[0];
    const float* p_mask = (const float*)d_in[1];
    const float* W_pre  = (const float*)d_in[2];
    const float* W_post = (const float*)d_in[3];
    const float* W_res  = (const float*)d_in[4];
    const float* b_pre  = (const float*)d_in[5];
    const float* b_post = (const float*)d_in[6];
    const float* b_res  = (const float*)d_in[7];
    const float* a_pre  = (const float*)d_in[8];
    const float* a_post = (const float*)d_in[9];
    const float* a_res  = (const float*)d_in[10];
    const float* ln_g   = (const float*)d_in[11];
    const float* ln_b   = (const float*)d_in[12];
    const float* W1     = (const float*)d_in[13];
    const float* b1     = (const float*)d_in[14];
    const float* W2     = (const float*)d_in[15];
    const float* b2     = (const float*)d_in[16];
    float* out = (float*)d_out;

    prep_kernel<<<265, 512, 0, stream>>>(W_pre, W_post, W_res, W1, W2, ln_g, ln_b, b1);
    fused_kernel<<<NBLK, 512, 0, stream>>>(p, p_mask, b_pre, b_post, b_res,
                                           a_pre, a_post, a_res, b2, out);
}

// Round 6
// 78.056 us; speedup vs baseline: 1.6421x; 1.6421x over previous
//
#include <hip/hip_runtime.h>
#include <stdint.h>

// Problem constants (B=1, L=256, C=128, N=4, TN=4)
#define LLTOT 65536
#define CDIM  128
#define TPIX  32

typedef float f32x4 __attribute__((ext_vector_type(4)));
typedef short s16x8 __attribute__((ext_vector_type(8)));

#define MFMA16(a, b, c) __builtin_amdgcn_mfma_f32_16x16x32_bf16((a), (b), (c), 0, 0, 0)

// ---- persistent device scratch ----
// fragment-linear layouts: [tile][kk][lane 0..63][8 bf16]  (lane: row = l&15, k-chunk = l>>4)
__device__ __align__(16) unsigned short g_wefff[2 * 4 * 64 * 8];    // routing weights (rows 24-31 zero)
__device__ __align__(16) unsigned short g_w1gf[32 * 4 * 64 * 8];    // W1 * ln_g
__device__ __align__(16) unsigned short g_w2f [8 * 16 * 64 * 8];    // W2
__device__ __align__(16) float  g_hA[512];                          // b1 + W1 @ ln_b
__device__ __align__(16) float  g_w1gs[512];                        // row sums of W1*ln_g
__device__ __align__(16) float  g_A[LLTOT * 4];                     // r_m + hpost_m * s_pre
__device__ __align__(16) float  g_B[LLTOT * 4];                     // hpost_m * mask
__device__ __align__(16) float2 g_simi[LLTOT];                      // (s*istd, s*mean*istd)
__device__ __align__(16) unsigned short g_pbf[LLTOT * CDIM];        // bf16 p in fragment layout [tile16][kk][lane][8]

__device__ __forceinline__ unsigned short f2bf(float f) {
    union { float f; uint32_t u; } v; v.f = f;
    uint32_t u = v.u;
    return (unsigned short)((u + 0x7FFFu + ((u >> 16) & 1u)) >> 16);
}
__device__ __forceinline__ uint32_t pack2(float a, float b) {
    return (uint32_t)f2bf(a) | ((uint32_t)f2bf(b) << 16);
}
__device__ __forceinline__ float bf2f(uint32_t lo16) { return __uint_as_float(lo16 << 16); }

__device__ __forceinline__ float fast_tanh(float x) {
    float cx = fminf(fmaxf(x, -10.f), 10.f);
    float e = __expf(2.f * cx);
    return (e - 1.f) * __builtin_amdgcn_rcpf(e + 1.f);
}
__device__ __forceinline__ float fast_sig(float z) {
    return __builtin_amdgcn_rcpf(1.f + __expf(-z));
}

// ---- prep: fold weights, convert to bf16, write fragment-linear layouts ----
__global__ void prep_kernel(const float* __restrict__ Wpre, const float* __restrict__ Wpost,
                            const float* __restrict__ Wres, const float* __restrict__ W1,
                            const float* __restrict__ W2, const float* __restrict__ ln_g,
                            const float* __restrict__ ln_b, const float* __restrict__ b1) {
    int b = blockIdx.x, t = threadIdx.x;
    if (b == 264) {
        int j = t;   // 512 threads
        float sg = 0.f, sb = 0.f;
        const float* row = W1 + j * 128;
        #pragma unroll 4
        for (int c = 0; c < 128; c += 4) {
            float4 wv = *(const float4*)(row + c);
            float4 gv = *(const float4*)(ln_g + c);
            float4 bv = *(const float4*)(ln_b + c);
            sg += wv.x*gv.x + wv.y*gv.y + wv.z*gv.z + wv.w*gv.w;
            sb += wv.x*bv.x + wv.y*bv.y + wv.z*bv.z + wv.w*bv.w;
        }
        g_hA[j]   = b1[j] + sb;
        g_w1gs[j] = sg;
        return;
    }
    int idx = b * 512 + t;
    if (idx < 4096) {
        // weff fragments: d -> (tile,kk,lane,e)
        int e = idx & 7, lane = (idx >> 3) & 63, kk = (idx >> 9) & 3, tile = idx >> 11;
        int o = tile * 16 + (lane & 15);
        int c = kk * 32 + (lane >> 4) * 8 + e;
        float v = 0.f;
        if (o < 4)        v = Wpre[o*512+c] + Wpre[o*512+128+c] + Wpre[o*512+256+c] + Wpre[o*512+384+c];
        else if (o < 8)   { int j = o - 4;  v = Wpost[j*512+c] + Wpost[j*512+128+c] + Wpost[j*512+256+c] + Wpost[j*512+384+c]; }
        else if (o < 24)  { int j = o - 8;  v = Wres[j*512+c] + Wres[j*512+128+c] + Wres[j*512+256+c] + Wres[j*512+384+c]; }
        g_wefff[idx] = f2bf(v);
    } else if (idx < 69632) {
        int d = idx - 4096;
        int e = d & 7, lane = (d >> 3) & 63, kk = (d >> 9) & 3, jt = d >> 11;
        int j = jt * 16 + (lane & 15);
        int c = kk * 32 + (lane >> 4) * 8 + e;
        g_w1gf[d] = f2bf(W1[j * 128 + c] * ln_g[c]);
    } else if (idx < 135168) {
        int d = idx - 69632;
        int e = d & 7, lane = (d >> 3) & 63, kk = (d >> 9) & 15, ct = d >> 13;
        int c = ct * 16 + (lane & 15);
        int k = kk * 32 + (lane >> 4) * 8 + e;
        g_w2f[d] = f2bf(W2[c * 512 + k]);
    }
}

// ---- K1: wave-autonomous routing + Sinkhorn, no barriers, no LDS ----
__global__ void __launch_bounds__(256, 4) route_kernel(
    const float* __restrict__ p, const float* __restrict__ p_mask,
    const float* __restrict__ b_pre, const float* __restrict__ b_post, const float* __restrict__ b_res,
    const float* __restrict__ a_pre, const float* __restrict__ a_post, const float* __restrict__ a_res)
{
    const int l = threadIdx.x & 63;
    const int gw = (int)((blockIdx.x * 256 + threadIdx.x) >> 6);   // 16-pixel tile id, 0..4095
    const int g = l >> 4, pixl = l & 15;
    const size_t gpix = (size_t)gw * 16 + pixl;

    // load p in fragment layout (pixel = l&15, chans g*8 + kk*32 .. +8), stats, bf16 convert
    float s = 0.f, ss = 0.f;
    s16x8 pf[4];
    const float* prow = p + gpix * 128 + g * 8;
    #pragma unroll
    for (int kk = 0; kk < 4; ++kk) {
        float4 va = *(const float4*)(prow + kk * 32);
        float4 vb = *(const float4*)(prow + kk * 32 + 4);
        s  += va.x + va.y + va.z + va.w + vb.x + vb.y + vb.z + vb.w;
        ss += va.x*va.x + va.y*va.y + va.z*va.z + va.w*va.w
            + vb.x*vb.x + vb.y*vb.y + vb.z*vb.z + vb.w*vb.w;
        s16x8 f;
        f[0] = (short)f2bf(va.x); f[1] = (short)f2bf(va.y);
        f[2] = (short)f2bf(va.z); f[3] = (short)f2bf(va.w);
        f[4] = (short)f2bf(vb.x); f[5] = (short)f2bf(vb.y);
        f[6] = (short)f2bf(vb.z); f[7] = (short)f2bf(vb.w);
        pf[kk] = f;
        *(s16x8*)(g_pbf + ((size_t)(gw * 4 + kk) * 64 + l) * 8) = f;   // coalesced 16B/lane
    }
    s  += __shfl_xor(s, 16);  ss += __shfl_xor(ss, 16);
    s  += __shfl_xor(s, 32);  ss += __shfl_xor(ss, 32);
    float mu = s * (1.f / 128.f), mq = ss * (1.f / 128.f);
    float rv  = rsqrtf(mq + 1.1920929e-07f);
    float var = mq - mu * mu;

    // routing mini-GEMM: y[o][pix], o = 0..23 over two 16-row tiles
    f32x4 y1 = {0.f, 0.f, 0.f, 0.f}, y2 = {0.f, 0.f, 0.f, 0.f};
    #pragma unroll
    for (int kk = 0; kk < 4; ++kk) {
        s16x8 a0 = *(const s16x8*)(g_wefff + ((size_t)(kk) * 64 + l) * 8);
        s16x8 a1 = *(const s16x8*)(g_wefff + ((size_t)(4 + kk) * 64 + l) * 8);
        y1 = MFMA16(a0, pf[kk], y1);
        y2 = MFMA16(a1, pf[kk], y2);
    }
    #pragma unroll
    for (int r = 0; r < 4; ++r) { y1[r] *= rv; y2[r] *= rv; }

    float apre = a_pre[0], apost = a_post[0], ares = a_res[0];

    // H_pre sum (real in g0 lanes, o = 0..3)
    float sp_loc = 0.f;
    #pragma unroll
    for (int r = 0; r < 4; ++r)
        sp_loc += fast_sig(apre * fast_tanh(y1[r]) + b_pre[r]);
    float sp = __shfl(sp_loc, pixl);   // broadcast from g0 lane of this pixel

    // H_post (real in g1 lanes, o = 4..7)
    float hp0 = 2.f * fast_sig(apost * fast_tanh(y1[0]) + b_post[0]);
    float hp1 = 2.f * fast_sig(apost * fast_tanh(y1[1]) + b_post[1]);
    float hp2 = 2.f * fast_sig(apost * fast_tanh(y1[2]) + b_post[2]);
    float hp3 = 2.f * fast_sig(apost * fast_tanh(y1[3]) + b_post[3]);

    // M row per lane-group: m = (g+2)&3; row regs = tile2 for g<2 else tile1
    int m = (g + 2) & 3;
    bool lo = g < 2;
    float M0 = __expf(ares * fast_tanh(lo ? y2[0] : y1[0]) + b_res[m * 4 + 0]);
    float M1 = __expf(ares * fast_tanh(lo ? y2[1] : y1[1]) + b_res[m * 4 + 1]);
    float M2 = __expf(ares * fast_tanh(lo ? y2[2] : y1[2]) + b_res[m * 4 + 2]);
    float M3 = __expf(ares * fast_tanh(lo ? y2[3] : y1[3]) + b_res[m * 4 + 3]);
    #pragma unroll 1
    for (int it = 0; it < 20; ++it) {
        float ri = __builtin_amdgcn_rcpf(M0 + M1 + M2 + M3);      // row normalize
        M0 *= ri; M1 *= ri; M2 *= ri; M3 *= ri;
        float c0 = M0, c1 = M1, c2 = M2, c3 = M3;                 // col sums over the 4 groups
        c0 += __shfl_xor(c0, 16); c1 += __shfl_xor(c1, 16); c2 += __shfl_xor(c2, 16); c3 += __shfl_xor(c3, 16);
        c0 += __shfl_xor(c0, 32); c1 += __shfl_xor(c1, 32); c2 += __shfl_xor(c2, 32); c3 += __shfl_xor(c3, 32);
        M0 *= __builtin_amdgcn_rcpf(c0); M1 *= __builtin_amdgcn_rcpf(c1);
        M2 *= __builtin_amdgcn_rcpf(c2); M3 *= __builtin_amdgcn_rcpf(c3);
    }
    float rm = M0 + M1 + M2 + M3;   // row sum of final doubly-stochastic M, row m

    // gather hp_m from the g1 lane of this pixel
    float h0b = __shfl(hp0, pixl + 16);
    float h1b = __shfl(hp1, pixl + 16);
    float h2b = __shfl(hp2, pixl + 16);
    float h3b = __shfl(hp3, pixl + 16);
    float hpm = (m & 2) ? ((m & 1) ? h3b : h2b) : ((m & 1) ? h1b : h0b);

    float msk = p_mask[gpix];
    g_A[gpix * 4 + m] = rm + hpm * sp;
    g_B[gpix * 4 + m] = hpm * msk;
    if (l < 16) {
        float istd = rsqrtf(sp * sp * var + 1e-5f);
        g_simi[gpix] = make_float2(sp * istd, sp * mu * istd);
    }
}

// ---- K2: MLP (GEMM1 -> h_s -> GEMM2) + epilogue, ONE barrier ----
__global__ void __launch_bounds__(512, 4) mlp_kernel(const float* __restrict__ b2g,
                                                     float* __restrict__ out)
{
    __shared__ __align__(16) unsigned short h_s[TPIX * 512];   // 32 KB bf16 relu(h), swizzle <<5

    const int t = threadIdx.x;
    const int w = t >> 6, l = t & 63, lr = l & 15, lk = l >> 4;
    const int blk = blockIdx.x;
    const size_t base = (size_t)blk * 32;

    // B fragments for both 16-pixel halves (coalesced 16B lane loads)
    s16x8 pf[2][4];
    #pragma unroll
    for (int it = 0; it < 2; ++it)
        #pragma unroll
        for (int kk = 0; kk < 4; ++kk)
            pf[it][kk] = *(const s16x8*)(g_pbf + ((size_t)((blk * 2 + it) * 4 + kk) * 64 + l) * 8);

    // per-pixel fold scalars
    float2 sim0 = g_simi[base + lr];
    float2 sim1 = g_simi[base + 16 + lr];

    // GEMM1: acc1[jt][it] = W1g[j,:] . p[i,:]
    f32x4 acc1[4][2] = {};
    #pragma unroll
    for (int kk = 0; kk < 4; ++kk)
        #pragma unroll
        for (int jt = 0; jt < 4; ++jt) {
            s16x8 a = *(const s16x8*)(g_w1gf + ((size_t)((w * 4 + jt) * 4 + kk) * 64 + l) * 8);
            acc1[jt][0] = MFMA16(a, pf[0][kk], acc1[jt][0]);
            acc1[jt][1] = MFMA16(a, pf[1][kk], acc1[jt][1]);
        }

    // fold LN scalars + bias + relu -> bf16 h_s
    #pragma unroll
    for (int jt = 0; jt < 4; ++jt) {
        int j0 = w * 64 + jt * 16 + lk * 4;
        float4 wg = *(const float4*)(g_w1gs + j0);
        float4 ha = *(const float4*)(g_hA + j0);
        #pragma unroll
        for (int it = 0; it < 2; ++it) {
            int i = it * 16 + lr;
            float si = it ? sim1.x : sim0.x;
            float mi = it ? sim1.y : sim0.y;
            f32x4 v = acc1[jt][it];
            float h0 = fmaxf(fmaf(si, v[0], fmaf(-mi, wg.x, ha.x)), 0.f);
            float h1 = fmaxf(fmaf(si, v[1], fmaf(-mi, wg.y, ha.y)), 0.f);
            float h2 = fmaxf(fmaf(si, v[2], fmaf(-mi, wg.z, ha.z)), 0.f);
            float h3 = fmaxf(fmaf(si, v[3], fmaf(-mi, wg.w, ha.w)), 0.f);
            uint2 uu;
            uu.x = pack2(h0, h1);
            uu.y = pack2(h2, h3);
            uint32_t off = (uint32_t)(i * 1024 + j0 * 2) ^ ((i & 7) << 5);
            *(uint2*)((char*)h_s + off) = uu;
        }
    }
    __syncthreads();

    // GEMM2: D[c, i] = W2[c,:] . h[i,:], wave w owns channels w*16..w*16+15
    f32x4 acc2[2] = {};
    #pragma unroll 4
    for (int kk = 0; kk < 16; ++kk) {
        s16x8 a = *(const s16x8*)(g_w2f + ((size_t)(w * 16 + kk) * 64 + l) * 8);
        s16x8 b0, b1;
        {
            uint32_t off = (uint32_t)(lr * 1024 + kk * 64 + lk * 16) ^ ((lr & 7) << 5);
            b0 = *(const s16x8*)((const char*)h_s + off);
        }
        {
            int i = 16 + lr;
            uint32_t off = (uint32_t)(i * 1024 + kk * 64 + lk * 16) ^ ((i & 7) << 5);
            b1 = *(const s16x8*)((const char*)h_s + off);
        }
        acc2[0] = MFMA16(a, b0, acc2[0]);
        acc2[1] = MFMA16(a, b1, acc2[1]);
    }

    // epilogue: out[i,m,c] = A_im * p[c] + B_im * (D + b2), plain stores
    const int c0 = w * 16 + lk * 4;
    float4 b2v = *(const float4*)(b2g + c0);
    #pragma unroll
    for (int it = 0; it < 2; ++it) {
        int i = it * 16 + lr;
        f32x4 Av = *(const f32x4*)(g_A + (base + i) * 4);
        f32x4 Bv = *(const f32x4*)(g_B + (base + i) * 4);
        // p[c0..c0+3] from fragment-layout g_pbf (L2-hot)
        uint2 pb = *(const uint2*)(g_pbf
                     + ((size_t)((blk * 2 + it) * 4 + (w >> 1)) * 64
                        + ((w & 1) * 2 + (lk >> 1)) * 16 + lr) * 8
                     + (lk & 1) * 4);
        float p0 = bf2f(pb.x & 0xffffu), p1 = __uint_as_float(pb.x & 0xffff0000u);
        float p2 = bf2f(pb.y & 0xffffu), p3 = __uint_as_float(pb.y & 0xffff0000u);
        float d0 = acc2[it][0] + b2v.x, d1 = acc2[it][1] + b2v.y;
        float d2 = acc2[it][2] + b2v.z, d3 = acc2[it][3] + b2v.w;
        float* og = out + (base + i) * 512 + c0;
        #pragma unroll
        for (int m = 0; m < 4; ++m) {
            f32x4 o;
            o[0] = Av[m] * p0 + Bv[m] * d0;
            o[1] = Av[m] * p1 + Bv[m] * d1;
            o[2] = Av[m] * p2 + Bv[m] * d2;
            o[3] = Av[m] * p3 + Bv[m] * d3;
            *(f32x4*)(og + m * 128) = o;
        }
    }
}

extern "C" void kernel_launch(void* const* d_in, const int* in_sizes, int n_in,
                              void* d_out, int out_size, void* d_ws, size_t ws_size,
                              hipStream_t stream) {
    const float* p      = (const float*)d_in[0];
    const float* p_mask = (const float*)d_in[1];
    const float* W_pre  = (const float*)d_in[2];
    const float* W_post = (const float*)d_in[3];
    const float* W_res  = (const float*)d_in[4];
    const float* b_pre  = (const float*)d_in[5];
    const float* b_post = (const float*)d_in[6];
    const float* b_res  = (const float*)d_in[7];
    const float* a_pre  = (const float*)d_in[8];
    const float* a_post = (const float*)d_in[9];
    const float* a_res  = (const float*)d_in[10];
    const float* ln_g   = (const float*)d_in[11];
    const float* ln_b   = (const float*)d_in[12];
    const float* W1     = (const float*)d_in[13];
    const float* b1     = (const float*)d_in[14];
    const float* W2     = (const float*)d_in[15];
    const float* b2     = (const float*)d_in[16];
    float* out = (float*)d_out;

    prep_kernel<<<265, 512, 0, stream>>>(W_pre, W_post, W_res, W1, W2, ln_g, ln_b, b1);
    route_kernel<<<1024, 256, 0, stream>>>(p, p_mask, b_pre, b_post, b_res,
                                           a_pre, a_post, a_res);
    mlp_kernel<<<2048, 512, 0, stream>>>(b2, out);
}

// Round 7
// 74.891 us; speedup vs baseline: 1.7115x; 1.0423x over previous
//
#include <hip/hip_runtime.h>
#include <stdint.h>

// Problem constants (B=1, L=256, C=128, N=4, TN=4)
#define LLTOT 65536
#define CDIM  128
#define TPIX  32

typedef float f32x4 __attribute__((ext_vector_type(4)));
typedef short s16x8 __attribute__((ext_vector_type(8)));

#define MFMA16(a, b, c) __builtin_amdgcn_mfma_f32_16x16x32_bf16((a), (b), (c), 0, 0, 0)

// ---- persistent device scratch (weights only) ----
// fragment-linear layouts: [tile][kk][lane 0..63][8 bf16]  (lane: row = l&15, k-chunk = l>>4)
__device__ __align__(16) unsigned short g_wefff[2 * 4 * 64 * 8];    // routing weights (rows 24-31 zero)
__device__ __align__(16) unsigned short g_w1gf[32 * 4 * 64 * 8];    // W1 * ln_g
__device__ __align__(16) unsigned short g_w2f [8 * 16 * 64 * 8];    // W2
__device__ __align__(16) float  g_hA[512];                          // b1 + W1 @ ln_b
__device__ __align__(16) float  g_w1gs[512];                        // row sums of W1*ln_g

__device__ __forceinline__ unsigned short f2bf(float f) {
    union { float f; uint32_t u; } v; v.f = f;
    uint32_t u = v.u;
    return (unsigned short)((u + 0x7FFFu + ((u >> 16) & 1u)) >> 16);
}
__device__ __forceinline__ uint32_t pack2(float a, float b) {
    return (uint32_t)f2bf(a) | ((uint32_t)f2bf(b) << 16);
}
__device__ __forceinline__ float bf2f(uint32_t lo16) { return __uint_as_float(lo16 << 16); }

__device__ __forceinline__ float fast_tanh(float x) {
    float cx = fminf(fmaxf(x, -10.f), 10.f);
    float e = __expf(2.f * cx);
    return (e - 1.f) * __builtin_amdgcn_rcpf(e + 1.f);
}
__device__ __forceinline__ float fast_sig(float z) {
    return __builtin_amdgcn_rcpf(1.f + __expf(-z));
}

// ---- prep: fold weights, convert to bf16, write fragment-linear layouts ----
__global__ void prep_kernel(const float* __restrict__ Wpre, const float* __restrict__ Wpost,
                            const float* __restrict__ Wres, const float* __restrict__ W1,
                            const float* __restrict__ W2, const float* __restrict__ ln_g,
                            const float* __restrict__ ln_b, const float* __restrict__ b1) {
    int b = blockIdx.x, t = threadIdx.x;
    if (b == 264) {
        int j = t;   // 512 threads
        float sg = 0.f, sb = 0.f;
        const float* row = W1 + j * 128;
        #pragma unroll 4
        for (int c = 0; c < 128; c += 4) {
            float4 wv = *(const float4*)(row + c);
            float4 gv = *(const float4*)(ln_g + c);
            float4 bv = *(const float4*)(ln_b + c);
            sg += wv.x*gv.x + wv.y*gv.y + wv.z*gv.z + wv.w*gv.w;
            sb += wv.x*bv.x + wv.y*bv.y + wv.z*bv.z + wv.w*bv.w;
        }
        g_hA[j]   = b1[j] + sb;
        g_w1gs[j] = sg;
        return;
    }
    int idx = b * 512 + t;
    if (idx < 4096) {
        // weff fragments: d -> (tile,kk,lane,e)
        int e = idx & 7, lane = (idx >> 3) & 63, kk = (idx >> 9) & 3, tile = idx >> 11;
        int o = tile * 16 + (lane & 15);
        int c = kk * 32 + (lane >> 4) * 8 + e;
        float v = 0.f;
        if (o < 4)        v = Wpre[o*512+c] + Wpre[o*512+128+c] + Wpre[o*512+256+c] + Wpre[o*512+384+c];
        else if (o < 8)   { int j = o - 4;  v = Wpost[j*512+c] + Wpost[j*512+128+c] + Wpost[j*512+256+c] + Wpost[j*512+384+c]; }
        else if (o < 24)  { int j = o - 8;  v = Wres[j*512+c] + Wres[j*512+128+c] + Wres[j*512+256+c] + Wres[j*512+384+c]; }
        g_wefff[idx] = f2bf(v);
    } else if (idx < 69632) {
        int d = idx - 4096;
        int e = d & 7, lane = (d >> 3) & 63, kk = (d >> 9) & 3, jt = d >> 11;
        int j = jt * 16 + (lane & 15);
        int c = kk * 32 + (lane >> 4) * 8 + e;
        g_w1gf[d] = f2bf(W1[j * 128 + c] * ln_g[c]);
    } else if (idx < 135168) {
        int d = idx - 69632;
        int e = d & 7, lane = (d >> 3) & 63, kk = (d >> 9) & 15, ct = d >> 13;
        int c = ct * 16 + (lane & 15);
        int k = kk * 32 + (lane >> 4) * 8 + e;
        g_w2f[d] = f2bf(W2[c * 512 + k]);
    }
}

// ---- fused: waves 0-1 route (barrier-free, in-register) ; all waves MLP ; 2 barriers ----
__global__ void __launch_bounds__(512, 4) fused_kernel(
    const float* __restrict__ p, const float* __restrict__ p_mask,
    const float* __restrict__ b_pre, const float* __restrict__ b_post, const float* __restrict__ b_res,
    const float* __restrict__ a_pre, const float* __restrict__ a_post, const float* __restrict__ a_res,
    const float* __restrict__ b2g, float* __restrict__ out)
{
    __shared__ __align__(16) unsigned short pf_lds[8 * 64 * 8];   // 8 KB bf16 p fragments [tile2*kk4][lane][8]
    __shared__ __align__(16) unsigned short h_s[TPIX * 512];      // 32 KB bf16 relu(h), swizzle <<5
    __shared__ __align__(16) float A_s[TPIX * 4], B_s[TPIX * 4];  // 1 KB
    __shared__ __align__(16) float2 simi_s[TPIX];                 // 256 B

    const int t = threadIdx.x;
    const int w = t >> 6, l = t & 63, lr = l & 15, lk = l >> 4;
    const size_t base = (size_t)blockIdx.x * 32;

    // ======== waves 0-1: full route for this block's 32 pixels (no barriers inside) ========
    if (w < 2) {
        const int g = lk, pixl = lr;
        const size_t gpix = base + w * 16 + pixl;

        // load p (fragment layout), stats, bf16 convert -> regs + LDS
        float s = 0.f, ss = 0.f;
        s16x8 pf[4];
        const float* prow = p + gpix * 128 + g * 8;
        #pragma unroll
        for (int kk = 0; kk < 4; ++kk) {
            float4 va = *(const float4*)(prow + kk * 32);
            float4 vb = *(const float4*)(prow + kk * 32 + 4);
            s  += va.x + va.y + va.z + va.w + vb.x + vb.y + vb.z + vb.w;
            ss += va.x*va.x + va.y*va.y + va.z*va.z + va.w*va.w
                + vb.x*vb.x + vb.y*vb.y + vb.z*vb.z + vb.w*vb.w;
            s16x8 f;
            f[0] = (short)f2bf(va.x); f[1] = (short)f2bf(va.y);
            f[2] = (short)f2bf(va.z); f[3] = (short)f2bf(va.w);
            f[4] = (short)f2bf(vb.x); f[5] = (short)f2bf(vb.y);
            f[6] = (short)f2bf(vb.z); f[7] = (short)f2bf(vb.w);
            pf[kk] = f;
            *(s16x8*)(pf_lds + (size_t)(w * 4 + kk) * 512 + l * 8) = f;
        }
        s  += __shfl_xor(s, 16);  ss += __shfl_xor(ss, 16);
        s  += __shfl_xor(s, 32);  ss += __shfl_xor(ss, 32);
        float mu = s * (1.f / 128.f), mq = ss * (1.f / 128.f);
        float rv  = rsqrtf(mq + 1.1920929e-07f);
        float var = mq - mu * mu;

        // routing mini-GEMM
        f32x4 y1 = {0.f, 0.f, 0.f, 0.f}, y2 = {0.f, 0.f, 0.f, 0.f};
        #pragma unroll
        for (int kk = 0; kk < 4; ++kk) {
            s16x8 a0 = *(const s16x8*)(g_wefff + ((size_t)(kk) * 64 + l) * 8);
            s16x8 a1 = *(const s16x8*)(g_wefff + ((size_t)(4 + kk) * 64 + l) * 8);
            y1 = MFMA16(a0, pf[kk], y1);
            y2 = MFMA16(a1, pf[kk], y2);
        }
        #pragma unroll
        for (int r = 0; r < 4; ++r) { y1[r] *= rv; y2[r] *= rv; }

        float apre = a_pre[0], apost = a_post[0], ares = a_res[0];

        // H_pre sum (real in g0 lanes, o = 0..3)
        float sp_loc = 0.f;
        #pragma unroll
        for (int r = 0; r < 4; ++r)
            sp_loc += fast_sig(apre * fast_tanh(y1[r]) + b_pre[r]);
        float sp = __shfl(sp_loc, pixl);

        // H_post (real in g1 lanes, o = 4..7)
        float hp0 = 2.f * fast_sig(apost * fast_tanh(y1[0]) + b_post[0]);
        float hp1 = 2.f * fast_sig(apost * fast_tanh(y1[1]) + b_post[1]);
        float hp2 = 2.f * fast_sig(apost * fast_tanh(y1[2]) + b_post[2]);
        float hp3 = 2.f * fast_sig(apost * fast_tanh(y1[3]) + b_post[3]);

        // Sinkhorn: M row per lane-group, m = (g+2)&3
        int m = (g + 2) & 3;
        bool lo = g < 2;
        float M0 = __expf(ares * fast_tanh(lo ? y2[0] : y1[0]) + b_res[m * 4 + 0]);
        float M1 = __expf(ares * fast_tanh(lo ? y2[1] : y1[1]) + b_res[m * 4 + 1]);
        float M2 = __expf(ares * fast_tanh(lo ? y2[2] : y1[2]) + b_res[m * 4 + 2]);
        float M3 = __expf(ares * fast_tanh(lo ? y2[3] : y1[3]) + b_res[m * 4 + 3]);
        #pragma unroll 1
        for (int it = 0; it < 20; ++it) {
            float ri = __builtin_amdgcn_rcpf(M0 + M1 + M2 + M3);
            M0 *= ri; M1 *= ri; M2 *= ri; M3 *= ri;
            float c0 = M0, c1 = M1, c2 = M2, c3 = M3;
            c0 += __shfl_xor(c0, 16); c1 += __shfl_xor(c1, 16); c2 += __shfl_xor(c2, 16); c3 += __shfl_xor(c3, 16);
            c0 += __shfl_xor(c0, 32); c1 += __shfl_xor(c1, 32); c2 += __shfl_xor(c2, 32); c3 += __shfl_xor(c3, 32);
            M0 *= __builtin_amdgcn_rcpf(c0); M1 *= __builtin_amdgcn_rcpf(c1);
            M2 *= __builtin_amdgcn_rcpf(c2); M3 *= __builtin_amdgcn_rcpf(c3);
        }
        float rm = M0 + M1 + M2 + M3;

        // gather hp_m from the g1 lane of this pixel
        float h0b = __shfl(hp0, pixl + 16);
        float h1b = __shfl(hp1, pixl + 16);
        float h2b = __shfl(hp2, pixl + 16);
        float h3b = __shfl(hp3, pixl + 16);
        float hpm = (m & 2) ? ((m & 1) ? h3b : h2b) : ((m & 1) ? h1b : h0b);

        float msk = p_mask[gpix];
        int pix = w * 16 + pixl;
        A_s[pix * 4 + m] = rm + hpm * sp;
        B_s[pix * 4 + m] = hpm * msk;
        if (l < 16) {
            float istd = rsqrtf(sp * sp * var + 1e-5f);
            simi_s[pix] = make_float2(sp * istd, sp * mu * istd);
        }
    }
    __syncthreads();

    // ======== GEMM1: acc1[jt][it] = W1g[j,:] . p[i,:] (pf from LDS) ========
    f32x4 acc1[4][2] = {};
    #pragma unroll
    for (int kk = 0; kk < 4; ++kk) {
        s16x8 b0 = *(const s16x8*)(pf_lds + (size_t)(kk) * 512 + l * 8);
        s16x8 b1 = *(const s16x8*)(pf_lds + (size_t)(4 + kk) * 512 + l * 8);
        #pragma unroll
        for (int jt = 0; jt < 4; ++jt) {
            s16x8 a = *(const s16x8*)(g_w1gf + ((size_t)((w * 4 + jt) * 4 + kk) * 64 + l) * 8);
            acc1[jt][0] = MFMA16(a, b0, acc1[jt][0]);
            acc1[jt][1] = MFMA16(a, b1, acc1[jt][1]);
        }
    }

    // fold LN scalars + bias + relu -> bf16 h_s
    {
        float2 sim0 = simi_s[lr];
        float2 sim1 = simi_s[16 + lr];
        #pragma unroll
        for (int jt = 0; jt < 4; ++jt) {
            int j0 = w * 64 + jt * 16 + lk * 4;
            float4 wg = *(const float4*)(g_w1gs + j0);
            float4 ha = *(const float4*)(g_hA + j0);
            #pragma unroll
            for (int it = 0; it < 2; ++it) {
                int i = it * 16 + lr;
                float si = it ? sim1.x : sim0.x;
                float mi = it ? sim1.y : sim0.y;
                f32x4 v = acc1[jt][it];
                float h0 = fmaxf(fmaf(si, v[0], fmaf(-mi, wg.x, ha.x)), 0.f);
                float h1 = fmaxf(fmaf(si, v[1], fmaf(-mi, wg.y, ha.y)), 0.f);
                float h2 = fmaxf(fmaf(si, v[2], fmaf(-mi, wg.z, ha.z)), 0.f);
                float h3 = fmaxf(fmaf(si, v[3], fmaf(-mi, wg.w, ha.w)), 0.f);
                uint2 uu;
                uu.x = pack2(h0, h1);
                uu.y = pack2(h2, h3);
                uint32_t off = (uint32_t)(i * 1024 + j0 * 2) ^ ((i & 7) << 5);
                *(uint2*)((char*)h_s + off) = uu;
            }
        }
    }
    __syncthreads();

    // ======== GEMM2: D[c,i] = W2[c,:] . h[i,:], wave w owns channels w*16.. ========
    f32x4 acc2[2] = {};
    #pragma unroll 4
    for (int kk = 0; kk < 16; ++kk) {
        s16x8 a = *(const s16x8*)(g_w2f + ((size_t)(w * 16 + kk) * 64 + l) * 8);
        s16x8 b0, b1;
        {
            uint32_t off = (uint32_t)(lr * 1024 + kk * 64 + lk * 16) ^ ((lr & 7) << 5);
            b0 = *(const s16x8*)((const char*)h_s + off);
        }
        {
            int i = 16 + lr;
            uint32_t off = (uint32_t)(i * 1024 + kk * 64 + lk * 16) ^ ((i & 7) << 5);
            b1 = *(const s16x8*)((const char*)h_s + off);
        }
        acc2[0] = MFMA16(a, b0, acc2[0]);
        acc2[1] = MFMA16(a, b1, acc2[1]);
    }

    // ======== epilogue: out[i,m,c] = A_im * p[c] + B_im * (D + b2) ========
    const int c0 = w * 16 + lk * 4;
    float4 b2v = *(const float4*)(b2g + c0);
    #pragma unroll
    for (int it = 0; it < 2; ++it) {
        int i = it * 16 + lr;
        f32x4 Av = *(const f32x4*)(A_s + i * 4);
        f32x4 Bv = *(const f32x4*)(B_s + i * 4);
        // p[c0..c0+3] from fragment-layout pf_lds
        const unsigned short* pe = pf_lds
            + ((size_t)(it * 4 + (w >> 1)) * 64 + ((w & 1) * 2 + (lk >> 1)) * 16 + lr) * 8
            + (lk & 1) * 4;
        uint2 pb = *(const uint2*)pe;
        float p0 = bf2f(pb.x & 0xffffu), p1 = __uint_as_float(pb.x & 0xffff0000u);
        float p2 = bf2f(pb.y & 0xffffu), p3 = __uint_as_float(pb.y & 0xffff0000u);
        float d0 = acc2[it][0] + b2v.x, d1 = acc2[it][1] + b2v.y;
        float d2 = acc2[it][2] + b2v.z, d3 = acc2[it][3] + b2v.w;
        float* og = out + (base + i) * 512 + c0;
        #pragma unroll
        for (int m = 0; m < 4; ++m) {
            f32x4 o;
            o[0] = Av[m] * p0 + Bv[m] * d0;
            o[1] = Av[m] * p1 + Bv[m] * d1;
            o[2] = Av[m] * p2 + Bv[m] * d2;
            o[3] = Av[m] * p3 + Bv[m] * d3;
            *(f32x4*)(og + m * 128) = o;
        }
    }
}

extern "C" void kernel_launch(void* const* d_in, const int* in_sizes, int n_in,
                              void* d_out, int out_size, void* d_ws, size_t ws_size,
                              hipStream_t stream) {
    const float* p      = (const float*)d_in[0];
    const float* p_mask = (const float*)d_in[1];
    const float* W_pre  = (const float*)d_in[2];
    const float* W_post = (const float*)d_in[3];
    const float* W_res  = (const float*)d_in[4];
    const float* b_pre  = (const float*)d_in[5];
    const float* b_post = (const float*)d_in[6];
    const float* b_res  = (const float*)d_in[7];
    const float* a_pre  = (const float*)d_in[8];
    const float* a_post = (const float*)d_in[9];
    const float* a_res  = (const float*)d_in[10];
    const float* ln_g   = (const float*)d_in[11];
    const float* ln_b   = (const float*)d_in[12];
    const float* W1     = (const float*)d_in[13];
    const float* b1     = (const float*)d_in[14];
    const float* W2     = (const float*)d_in[15];
    const float* b2     = (const float*)d_in[16];
    float* out = (float*)d_out;

    prep_kernel<<<265, 512, 0, stream>>>(W_pre, W_post, W_res, W1, W2, ln_g, ln_b, b1);
    fused_kernel<<<2048, 512, 0, stream>>>(p, p_mask, b_pre, b_post, b_res,
                                           a_pre, a_post, a_res, b2, out);
}